// Round 12
// baseline (651.399 us; speedup 1.0000x reference)
//
#include <hip/hip_runtime.h>
#include <stdint.h>
#include <stddef.h>

#define S_LEN 2048
#define B_N   4096
#define T_N   10
#define NCH   128
#define NEG_INF_F (-10000.0f)

template<int CTRL>
__device__ __forceinline__ int dppi(int v) {
    return __builtin_amdgcn_update_dpp(0, v, CTRL, 0xF, 0xF, true);
}
template<int CTRL>
__device__ __forceinline__ float dppf(float v) {
    return __int_as_float(dppi<CTRL>(__float_as_int(v)));
}

static __device__ __forceinline__ int imin(int a, int b) { return a < b ? a : b; }
static __device__ __forceinline__ int imax(int a, int b) { return a > b ? a : b; }

static __device__ __forceinline__ float vmax3(float a, float b, float c) {
    float d;
    asm("v_max3_f32 %0, %1, %2, %3" : "=v"(d) : "v"(a), "v"(b), "v"(c));
    return d;
}

// quad_perm cyclic rotations (probed at runtime, direction-agnostic)
#define QP1 0x39   // [1,2,3,0]
#define QP2 0x4E   // [2,3,0,1]
#define QP3 0x93   // [3,0,1,2]

// ---------------- F: value-only forward. 4 lanes/batch, 16 batches/wave, 256 waves ----------------
// Lane l holds fv[l], fv[4+l] + duplicated fv[8], fv[9]. Per step: 6 quad-perm DPPs +
// 4 independent 10-candidate max trees (plain VALU, compiler-scheduled builtins).
__global__ void __launch_bounds__(64) viterbi_fwd(const float* __restrict__ feats,
                                                  const float* __restrict__ trans,
                                                  const int* __restrict__ lengths,
                                                  float* __restrict__ ckpt) {
    const int tid = threadIdx.x;
    const int l   = tid & 3;
    const int b   = blockIdx.x * 16 + (tid >> 2);
    const int len = lengths[b];

    int lenW = len;
    lenW = imax(lenW, __shfl_xor(lenW, 4, 64));
    lenW = imax(lenW, __shfl_xor(lenW, 8, 64));
    lenW = imax(lenW, __shfl_xor(lenW, 16, 64));
    lenW = imax(lenW, __shfl_xor(lenW, 32, 64));
    lenW = __builtin_amdgcn_readfirstlane(lenW);

    // probe actual quad rotation source lanes (whatever the HW interpretation, these
    // are the lane indices whose registers the rotations deliver)
    const int q1 = dppi<QP1>(l);
    const int q2 = dppi<QP2>(l);
    const int q3 = dppi<QP3>(l);

    // per-lane outputs t = {l, 4+l, 8, 9}; tr tables keyed to probed sources
    int to[4] = { l, 4 + l, 8, 9 };
    float trAs[4], trA1[4], trA2[4], trA3[4];
    float trBs[4], trB1[4], trB2[4], trB3[4];
    float tr8[4], tr9[4];
    #pragma unroll
    for (int o = 0; o < 4; ++o) {
        const float* tr = trans + to[o] * T_N;
        trAs[o] = tr[l];      trA1[o] = tr[q1];     trA2[o] = tr[q2];     trA3[o] = tr[q3];
        trBs[o] = tr[4 + l];  trB1[o] = tr[4 + q1]; trB2[o] = tr[4 + q2]; trB3[o] = tr[4 + q3];
        tr8[o]  = tr[8];      tr9[o]  = tr[9];
    }

    // state: a=fv[l], bv=fv[4+l], f8=fv[8], f9=fv[9]   (START_TAG=8)
    float a = NEG_INF_F, bv = NEG_INF_F, f8 = 0.0f, f9 = NEG_INF_F;

    const float* fp = feats + (size_t)b * T_N;
    auto ldf = [&](int s, int k) -> float {
        return fp[(size_t)imin(s, S_LEN - 1) * (B_N * T_N) + to[k]];
    };

    float fA[32], fB[32];
    #pragma unroll
    for (int u = 0; u < 8; ++u) {
        #pragma unroll
        for (int k = 0; k < 4; ++k) fA[u * 4 + k] = ldf(u, k);
    }

    auto onestep = [&](const float* f) {
        float rA1 = dppf<QP1>(a),  rA2 = dppf<QP2>(a),  rA3 = dppf<QP3>(a);
        float rB1 = dppf<QP1>(bv), rB2 = dppf<QP2>(bv), rB3 = dppf<QP3>(bv);
        float m[4];
        #pragma unroll
        for (int o = 0; o < 4; ++o) {
            float c0 = a   + trAs[o], c1 = rA1 + trA1[o], c2 = rA2 + trA2[o], c3 = rA3 + trA3[o];
            float c4 = bv  + trBs[o], c5 = rB1 + trB1[o], c6 = rB2 + trB2[o], c7 = rB3 + trB3[o];
            float c8 = f8 + tr8[o],   c9 = f9 + tr9[o];
            float x0 = vmax3(c0, c1, c2);
            float x1 = vmax3(c3, c4, c5);
            float x2 = vmax3(c6, c7, c8);
            m[o] = fmaxf(vmax3(x0, x1, x2), c9);
        }
        a  = m[0] + f[0];
        bv = m[1] + f[1];
        f8 = m[2] + f[2];
        f9 = m[3] + f[3];
    };
    auto step8 = [&](float (&f)[32]) {
        #pragma unroll
        for (int u = 0; u < 8; ++u) onestep(&f[u * 4]);
    };
    auto loadinto = [&](float (&f)[32], int sbase) {
        #pragma unroll
        for (int u = 0; u < 8; ++u) {
            #pragma unroll
            for (int k = 0; k < 4; ++k) f[u * 4 + k] = ldf(sbase + u, k);
        }
    };
    auto ckstore = [&](int snext) {
        if (snext <= len && snext <= S_LEN - 16) {
            float* cp = ckpt + ((size_t)(snext >> 4) * B_N + b) * T_N;
            cp[l] = a; cp[4 + l] = bv;
            if (l == 0) { cp[8] = f8; cp[9] = f9; }
        }
    };

    for (int s0 = 0; s0 < lenW; s0 += 16) {
        loadinto(fB, s0 + 8);
        step8(fA);
        loadinto(fA, s0 + 16);
        step8(fB);
        ckstore(s0 + 16);
    }
}

// ---------------- A: parallel argmax recompute per (batch, 16-chunk) ----------------
__global__ void __launch_bounds__(256) bt_maps(const float* __restrict__ feats,
                                               const float* __restrict__ trans,
                                               const int* __restrict__ lengths,
                                               const float* __restrict__ ckpt,
                                               unsigned* __restrict__ bpd,
                                               unsigned char* __restrict__ bpb,
                                               uint2* __restrict__ gmap,
                                               float* __restrict__ lastfv) {
    const int c = blockIdx.x >> 4;                          // 0..127
    const int b = ((blockIdx.x & 15) << 8) + threadIdx.x;   // 0..4095
    const int len = lengths[b];
    const int r0 = c * 16;
    const int kl = len - r0;   // lastfv snapshot iteration if 0..16

    if (kl < 0) {   // chunk entirely beyond len
        gmap[(size_t)c * B_N + b] = make_uint2(0x76543210u, 0x98u);
        return;
    }

    float fv[T_N];
    if (c == 0) {
        #pragma unroll
        for (int p = 0; p < T_N; ++p) fv[p] = (p == 8) ? 0.0f : NEG_INF_F;
    } else {
        #pragma unroll
        for (int p = 0; p < T_N; ++p) fv[p] = ckpt[((size_t)c * B_N + b) * T_N + p];
    }

    float* lfp = lastfv + (size_t)b * T_N;
    if (kl == 0) {   // fv here == fv_all[len]; no live rows in this chunk
        #pragma unroll
        for (int n = 0; n < T_N; ++n) lfp[n] = fv[n];
        gmap[(size_t)c * B_N + b] = make_uint2(0x76543210u, 0x98u);
        return;
    }

    const size_t rstride = (size_t)B_N * T_N;
    const float* fbase = feats + (size_t)b * T_N;

    float buf[T_N];
    {   // feat row r0 (r0 < len guaranteed)
        const float2* p2 = (const float2*)(fbase + (size_t)r0 * rstride);
        #pragma unroll
        for (int i = 0; i < 5; ++i) { float2 v = p2[i]; buf[2*i] = v.x; buf[2*i+1] = v.y; }
    }

    unsigned Glo = 0x76543210u, Ghi = 0x98u;

    // k = 0: fv update only (row r0's map belongs to chunk c-1)
    {
        float m[T_N];
        #pragma unroll
        for (int n = 0; n < T_N; ++n) {
            float cd[T_N];
            #pragma unroll
            for (int p = 0; p < T_N; ++p) cd[p] = fv[p] + trans[n * T_N + p];
            float x0 = vmax3(cd[0], cd[1], cd[2]);
            float x1 = vmax3(cd[3], cd[4], cd[5]);
            float x2 = vmax3(cd[6], cd[7], cd[8]);
            m[n] = fmaxf(vmax3(x0, x1, x2), cd[9]);
        }
        #pragma unroll
        for (int n = 0; n < T_N; ++n) fv[n] = m[n] + buf[n];
    }

    #pragma unroll 1
    for (int k = 1; k <= 16; ++k) {
        const int r = r0 + k;
        {   // issue next feat row load at top (hides under the row compute)
            const float2* p2 = (const float2*)(fbase + (size_t)imin(r, S_LEN - 1) * rstride);
            #pragma unroll
            for (int i = 0; i < 5; ++i) { float2 v = p2[i]; buf[2*i] = v.x; buf[2*i+1] = v.y; }
        }
        if (k == kl) {   // fv before this step == fv_all[len]
            #pragma unroll
            for (int n = 0; n < T_N; ++n) lfp[n] = fv[n];
        }
        unsigned mlo = 0, mhi = 0, nGlo = 0, nGhi = 0;
        unsigned long long G64 = ((unsigned long long)Ghi << 32) | Glo;
        float m[T_N];
        #pragma unroll
        for (int n = 0; n < T_N; ++n) {
            float cd[T_N];
            #pragma unroll
            for (int p = 0; p < T_N; ++p) cd[p] = fv[p] + trans[n * T_N + p];
            float x0 = vmax3(cd[0], cd[1], cd[2]);
            float x1 = vmax3(cd[3], cd[4], cd[5]);
            float x2 = vmax3(cd[6], cd[7], cd[8]);
            float mm = fmaxf(vmax3(x0, x1, x2), cd[9]);
            m[n] = mm;
            int ix = 9;
            #pragma unroll
            for (int p = 8; p >= 0; --p) ix = (cd[p] == mm) ? p : ix;   // first tie = min p
            unsigned nib = (unsigned)(G64 >> (ix << 2)) & 15u;
            if (n < 8) { mlo |= (unsigned)ix << (4 * n);       nGlo |= nib << (4 * n); }
            else       { mhi |= (unsigned)ix << (4 * (n - 8)); nGhi |= nib << (4 * (n - 8)); }
        }
        if (r < len) {
            bpd[(size_t)r * B_N + b] = mlo;
            bpb[(size_t)r * B_N + b] = (unsigned char)mhi;
            Glo = nGlo; Ghi = nGhi;
        }
        if (k < 16) {
            #pragma unroll
            for (int n = 0; n < T_N; ++n) fv[n] = m[n] + buf[n];
        }
    }

    gmap[(size_t)c * B_N + b] = make_uint2(Glo, Ghi);
}

// nibble-map apply: next = (w64 >> 4*cur) & 15
static __device__ __forceinline__ int bpapply(uint2 w, int cur) {
    unsigned long long w64 = ((unsigned long long)w.y << 32) | (unsigned long long)w.x;
    return (int)((w64 >> (cur * 4)) & 15ULL);
}

// ---------------- B: terminal score/argmax + compose 128 chunk maps per batch ----------------
__global__ void __launch_bounds__(256) bt_compose(const uint2* __restrict__ gmap,
                                                  const float* __restrict__ lastfv,
                                                  const float* __restrict__ trans,
                                                  unsigned char* __restrict__ entry,
                                                  float* __restrict__ score) {
    const int b = blockIdx.x * 256 + threadIdx.x;

    float term[T_N];
    #pragma unroll
    for (int n = 0; n < T_N; ++n)
        term[n] = lastfv[(size_t)b * T_N + n] + trans[9 * T_N + n];   // STOP row
    float x0 = vmax3(term[0], term[1], term[2]);
    float x1 = vmax3(term[3], term[4], term[5]);
    float x2 = vmax3(term[6], term[7], term[8]);
    float pm = fmaxf(vmax3(x0, x1, x2), term[9]);
    int st = 9;
    #pragma unroll
    for (int n = 8; n >= 0; --n) st = (term[n] == pm) ? n : st;
    score[b] = pm;

    uint2 wA[16], wB[16];
    auto pre = [&](uint2 (&W)[16], int cb) {
        #pragma unroll
        for (int u = 0; u < 16; ++u) W[u] = gmap[(size_t)(cb * 16 + u) * B_N + b];
    };
    auto proc = [&](uint2 (&W)[16], int cb) {
        #pragma unroll
        for (int u = 15; u >= 0; --u) {
            int cc = cb * 16 + u;
            entry[(size_t)cc * B_N + b] = (unsigned char)st;
            st = bpapply(W[u], st);
        }
    };
    pre(wA, 7);
    pre(wB, 6); proc(wA, 7);
    pre(wA, 5); proc(wB, 6);
    pre(wB, 4); proc(wA, 5);
    pre(wA, 3); proc(wB, 4);
    pre(wB, 2); proc(wA, 3);
    pre(wA, 1); proc(wB, 2);
    pre(wB, 0); proc(wA, 1);
    proc(wB, 0);
}

// ---------------- C: follow maps per (batch, chunk) from entry tag, emit path ----------------
__global__ void __launch_bounds__(256) bt_emit(const unsigned* __restrict__ bpd,
                                               const unsigned char* __restrict__ bpb,
                                               const int* __restrict__ lengths,
                                               const unsigned char* __restrict__ entry,
                                               float* __restrict__ opaths) {
    const int c = blockIdx.x >> 4;
    const int b = ((blockIdx.x & 15) << 8) + threadIdx.x;
    const int len = lengths[b];
    float* op = opaths + (size_t)b * S_LEN + c * 16;

    if (c * 16 >= len) {   // fully past len: all zeros, skip map loads
        float4 z = make_float4(0.f, 0.f, 0.f, 0.f);
        #pragma unroll
        for (int qq = 0; qq < 4; ++qq) *(float4*)(op + qq * 4) = z;
        return;
    }

    const int r0 = c * 16 + 1;
    unsigned Wd[16], Wb[16];
    #pragma unroll
    for (int u = 0; u < 16; ++u) {
        int r = r0 + u;
        unsigned d = 0x76543210u, h = 0x98u;   // identity
        if (r < len) { d = bpd[(size_t)r * B_N + b]; h = bpb[(size_t)r * B_N + b]; }
        Wd[u] = d; Wb[u] = h;
    }

    int cur = entry[(size_t)c * B_N + b];
    float buf[16];
    #pragma unroll
    for (int u = 15; u >= 0; --u) {
        unsigned long long w = ((unsigned long long)Wb[u] << 32) | Wd[u];
        cur = (int)((w >> ((cur * 4) & 63)) & 15ULL);
        buf[u] = (c * 16 + u < len) ? (float)cur : 0.0f;
    }
    #pragma unroll
    for (int qq = 0; qq < 4; ++qq)
        *(float4*)(op + qq * 4) = make_float4(buf[qq*4+0], buf[qq*4+1], buf[qq*4+2], buf[qq*4+3]);
}

extern "C" void kernel_launch(void* const* d_in, const int* in_sizes, int n_in,
                              void* d_out, int out_size, void* d_ws, size_t ws_size,
                              hipStream_t stream) {
    const float* feats   = (const float*)d_in[0];
    const float* trans   = (const float*)d_in[1];
    const int*   lengths = (const int*)d_in[2];
    float* out = (float*)d_out;

    // workspace layout (~67.8 MB)
    char* w = (char*)d_ws;
    float*         ckpt  = (float*)w;          w += (size_t)NCH * B_N * T_N * 4;       // 20,971,520
    unsigned*      bpd   = (unsigned*)w;       w += (size_t)(S_LEN + 1) * B_N * 4;     // 33,570,816
    unsigned char* bpb   = (unsigned char*)w;  w += (size_t)(S_LEN + 1) * B_N;         //  8,392,704
    uint2*         gmap  = (uint2*)w;          w += (size_t)NCH * B_N * 8;             //  4,194,304
    unsigned char* entry = (unsigned char*)w;  w += (size_t)NCH * B_N;                 //    524,288
    float*         lastfv = (float*)w;                                                 //    163,840

    viterbi_fwd<<<B_N / 16, 64, 0, stream>>>(feats, trans, lengths, ckpt);
    bt_maps   <<<NCH * (B_N / 256), 256, 0, stream>>>(feats, trans, lengths, ckpt, bpd, bpb, gmap, lastfv);
    bt_compose<<<B_N / 256, 256, 0, stream>>>(gmap, lastfv, trans, entry, out);
    bt_emit   <<<NCH * (B_N / 256), 256, 0, stream>>>(bpd, bpb, lengths, entry, out + B_N);
}

// Round 14
// 325.270 us; speedup vs baseline: 2.0026x; 2.0026x over previous
//
#include <hip/hip_runtime.h>
#include <stdint.h>
#include <stddef.h>

#define S_LEN 2048
#define B_N   4096
#define T_N   10
#define NCH   128
#define NEG_INF_F (-10000.0f)

template<int CTRL>
__device__ __forceinline__ int dppi(int v) {
    return __builtin_amdgcn_update_dpp(0, v, CTRL, 0xF, 0xF, true);
}

static __device__ __forceinline__ int imin(int a, int b) { return a < b ? a : b; }
static __device__ __forceinline__ int imax(int a, int b) { return a > b ? a : b; }

static __device__ __forceinline__ float vmax3(float a, float b, float c) {
    float d;
    asm("v_max3_f32 %0, %1, %2, %3" : "=v"(d) : "v"(a), "v"(b), "v"(c));
    return d;
}

// ---------------- F: value-only forward (round-9 measured-best: 200 us) ----------------
// 16 lanes/batch, 4 batches/wave, 16-step supersteps, triple-buffered feat prefetch.
__global__ void __launch_bounds__(256) viterbi_fwd(const float* __restrict__ feats,
                                                   const float* __restrict__ trans,
                                                   const int* __restrict__ lengths,
                                                   float* __restrict__ ckpt) {
    const float FNINF = __int_as_float(0xff800000);   // -inf
    const int tid = threadIdx.x;
    const int t   = tid & 15;
    const int b   = blockIdx.x * 16 + (tid >> 4);
    const bool act = (t < T_N);
    const int len = lengths[b];

    int lenW = len;
    lenW = imax(lenW, __shfl_xor(lenW, 16, 64));
    lenW = imax(lenW, __shfl_xor(lenW, 32, 64));
    lenW = __builtin_amdgcn_readfirstlane(lenW);

    // probe actual DPP ror source columns (direction-agnostic)
    int q[16];
    q[0]  = t;
    q[1]  = dppi<0x121>(t);  q[2]  = dppi<0x122>(t);  q[3]  = dppi<0x123>(t);
    q[4]  = dppi<0x124>(t);  q[5]  = dppi<0x125>(t);  q[6]  = dppi<0x126>(t);
    q[7]  = dppi<0x127>(t);  q[8]  = dppi<0x128>(t);  q[9]  = dppi<0x129>(t);
    q[10] = dppi<0x12A>(t);  q[11] = dppi<0x12B>(t);  q[12] = dppi<0x12C>(t);
    q[13] = dppi<0x12D>(t);  q[14] = dppi<0x12E>(t);  q[15] = dppi<0x12F>(t);

    float trr[16];
    #pragma unroll
    for (int r = 0; r < 16; ++r) {
        bool v = act && (q[r] < T_N);
        trr[r] = v ? trans[t * T_N + q[r]] : FNINF;   // tr[t][p_r]
    }

    const float* fptr = feats + (size_t)b * T_N + imin(t, T_N - 1);
    auto ldfeat = [&](int s) -> float {
        return fptr[(size_t)imin(s, S_LEN - 1) * (B_N * T_N)];
    };

    float fvr;
    {
        float finit = (t == 8) ? 0.0f : NEG_INF_F;   // START_TAG = 8
        asm("v_mov_b32 %0, %1\n\ts_nop 1" : "=v"(fvr) : "v"(finit));
    }

    float bA[16], bB[16], bC[16];
    #pragma unroll
    for (int u = 0; u < 16; ++u) bA[u] = ldfeat(u);
    #pragma unroll
    for (int u = 0; u < 16; ++u) bB[u] = ldfeat(16 + u);
    #pragma unroll
    for (int u = 0; u < 16; ++u) bC[u] = ldfeat(32 + u);

    auto step16 = [&](float (&f)[16]) {
        #pragma unroll
        for (int u = 0; u < 16; ++u) {
            float cd[16];
            cd[0] = fvr + trr[0];
#define DPPADD(N, S) asm("v_add_f32_dpp %0, %1, %2 " S " row_mask:0xf bank_mask:0xf" \
                         : "=v"(cd[N]) : "v"(fvr), "v"(trr[N]))
            DPPADD(1,  "row_ror:1");  DPPADD(2,  "row_ror:2");  DPPADD(3,  "row_ror:3");
            DPPADD(4,  "row_ror:4");  DPPADD(5,  "row_ror:5");  DPPADD(6,  "row_ror:6");
            DPPADD(7,  "row_ror:7");  DPPADD(8,  "row_ror:8");  DPPADD(9,  "row_ror:9");
            DPPADD(10, "row_ror:10"); DPPADD(11, "row_ror:11"); DPPADD(12, "row_ror:12");
            DPPADD(13, "row_ror:13"); DPPADD(14, "row_ror:14"); DPPADD(15, "row_ror:15");
#undef DPPADD
            float x0 = vmax3(cd[0],  cd[1],  cd[2]);
            float x1 = vmax3(cd[3],  cd[4],  cd[5]);
            float x2 = vmax3(cd[6],  cd[7],  cd[8]);
            float x3 = vmax3(cd[9],  cd[10], cd[11]);
            float x4 = vmax3(cd[12], cd[13], cd[14]);
            float y0 = vmax3(x0, x1, x2);
            float y1 = vmax3(x3, x4, cd[15]);
            float mm = fmaxf(y0, y1);
            // fvr producer + s_nop 1 covers the VALU-write -> DPP-read hazard
            asm("v_add_f32 %0, %1, %2\n\ts_nop 1" : "=v"(fvr) : "v"(mm), "v"(f[u]));
        }
    };
    auto ckstore = [&](int snext) {
        if (act && snext <= len && snext <= S_LEN - 16)
            ckpt[((size_t)(snext >> 4) * B_N + b) * T_N + t] = fvr;   // fv_all[snext]
    };

    for (int s0 = 0; s0 < lenW; s0 += 48) {
        step16(bA); ckstore(s0 + 16);
        #pragma unroll
        for (int u = 0; u < 16; ++u) bA[u] = ldfeat(s0 + 48 + u);

        step16(bB); ckstore(s0 + 32);
        #pragma unroll
        for (int u = 0; u < 16; ++u) bB[u] = ldfeat(s0 + 64 + u);

        step16(bC); ckstore(s0 + 48);
        #pragma unroll
        for (int u = 0; u < 16; ++u) bC[u] = ldfeat(s0 + 80 + u);
    }
}

// ---------------- A: parallel argmax recompute per (batch, 16-chunk) (round-10 measured-best) ----------------
__global__ void __launch_bounds__(256) bt_maps(const float* __restrict__ feats,
                                               const float* __restrict__ trans,
                                               const int* __restrict__ lengths,
                                               const float* __restrict__ ckpt,
                                               unsigned* __restrict__ bpd,
                                               unsigned char* __restrict__ bpb,
                                               uint2* __restrict__ gmap,
                                               float* __restrict__ lastfv) {
    const int c = blockIdx.x >> 4;                          // 0..127
    const int b = ((blockIdx.x & 15) << 8) + threadIdx.x;   // 0..4095
    const int len = lengths[b];
    const int r0 = c * 16;
    const int kl = len - r0;   // lastfv snapshot iteration if 0..16

    if (kl < 0) {   // chunk entirely beyond len
        gmap[(size_t)c * B_N + b] = make_uint2(0x76543210u, 0x98u);
        return;
    }

    float fv[T_N];
    if (c == 0) {
        #pragma unroll
        for (int p = 0; p < T_N; ++p) fv[p] = (p == 8) ? 0.0f : NEG_INF_F;
    } else {
        #pragma unroll
        for (int p = 0; p < T_N; ++p) fv[p] = ckpt[((size_t)c * B_N + b) * T_N + p];
    }

    float* lfp = lastfv + (size_t)b * T_N;
    if (kl == 0) {   // fv here == fv_all[len]; no live rows in this chunk
        #pragma unroll
        for (int n = 0; n < T_N; ++n) lfp[n] = fv[n];
        gmap[(size_t)c * B_N + b] = make_uint2(0x76543210u, 0x98u);
        return;
    }

    const size_t rstride = (size_t)B_N * T_N;
    const float* fbase = feats + (size_t)b * T_N;

    float buf[T_N];
    {   // feat row r0 (r0 < len guaranteed)
        const float2* p2 = (const float2*)(fbase + (size_t)r0 * rstride);
        #pragma unroll
        for (int i = 0; i < 5; ++i) { float2 v = p2[i]; buf[2*i] = v.x; buf[2*i+1] = v.y; }
    }

    unsigned Glo = 0x76543210u, Ghi = 0x98u;

    // k = 0: fv update only (row r0's map belongs to chunk c-1)
    {
        float m[T_N];
        #pragma unroll
        for (int n = 0; n < T_N; ++n) {
            float cd[T_N];
            #pragma unroll
            for (int p = 0; p < T_N; ++p) cd[p] = fv[p] + trans[n * T_N + p];
            float x0 = vmax3(cd[0], cd[1], cd[2]);
            float x1 = vmax3(cd[3], cd[4], cd[5]);
            float x2 = vmax3(cd[6], cd[7], cd[8]);
            m[n] = fmaxf(vmax3(x0, x1, x2), cd[9]);
        }
        #pragma unroll
        for (int n = 0; n < T_N; ++n) fv[n] = m[n] + buf[n];
    }

    #pragma unroll 1
    for (int k = 1; k <= 16; ++k) {
        const int r = r0 + k;
        {   // issue next feat row load at top (hides under the row compute)
            const float2* p2 = (const float2*)(fbase + (size_t)imin(r, S_LEN - 1) * rstride);
            #pragma unroll
            for (int i = 0; i < 5; ++i) { float2 v = p2[i]; buf[2*i] = v.x; buf[2*i+1] = v.y; }
        }
        if (k == kl) {   // fv before this step == fv_all[len]
            #pragma unroll
            for (int n = 0; n < T_N; ++n) lfp[n] = fv[n];
        }
        unsigned mlo = 0, mhi = 0, nGlo = 0, nGhi = 0;
        unsigned long long G64 = ((unsigned long long)Ghi << 32) | Glo;
        float m[T_N];
        #pragma unroll
        for (int n = 0; n < T_N; ++n) {
            float cd[T_N];
            #pragma unroll
            for (int p = 0; p < T_N; ++p) cd[p] = fv[p] + trans[n * T_N + p];
            float x0 = vmax3(cd[0], cd[1], cd[2]);
            float x1 = vmax3(cd[3], cd[4], cd[5]);
            float x2 = vmax3(cd[6], cd[7], cd[8]);
            float mm = fmaxf(vmax3(x0, x1, x2), cd[9]);
            m[n] = mm;
            int ix = 9;
            #pragma unroll
            for (int p = 8; p >= 0; --p) ix = (cd[p] == mm) ? p : ix;   // first tie = min p
            unsigned nib = (unsigned)(G64 >> (ix << 2)) & 15u;
            if (n < 8) { mlo |= (unsigned)ix << (4 * n);       nGlo |= nib << (4 * n); }
            else       { mhi |= (unsigned)ix << (4 * (n - 8)); nGhi |= nib << (4 * (n - 8)); }
        }
        if (r < len) {
            bpd[(size_t)r * B_N + b] = mlo;
            bpb[(size_t)r * B_N + b] = (unsigned char)mhi;
            Glo = nGlo; Ghi = nGhi;
        }
        if (k < 16) {
            #pragma unroll
            for (int n = 0; n < T_N; ++n) fv[n] = m[n] + buf[n];
        }
    }

    gmap[(size_t)c * B_N + b] = make_uint2(Glo, Ghi);
}

// nibble-map apply: next = (w64 >> 4*cur) & 15
static __device__ __forceinline__ int bpapply(uint2 w, int cur) {
    unsigned long long w64 = ((unsigned long long)w.y << 32) | (unsigned long long)w.x;
    return (int)((w64 >> (cur * 4)) & 15ULL);
}

// ---------------- B: terminal score/argmax + compose 128 chunk maps per batch ----------------
__global__ void __launch_bounds__(256) bt_compose(const uint2* __restrict__ gmap,
                                                  const float* __restrict__ lastfv,
                                                  const float* __restrict__ trans,
                                                  unsigned char* __restrict__ entry,
                                                  float* __restrict__ score) {
    const int b = blockIdx.x * 256 + threadIdx.x;

    float term[T_N];
    #pragma unroll
    for (int n = 0; n < T_N; ++n)
        term[n] = lastfv[(size_t)b * T_N + n] + trans[9 * T_N + n];   // STOP row
    float x0 = vmax3(term[0], term[1], term[2]);
    float x1 = vmax3(term[3], term[4], term[5]);
    float x2 = vmax3(term[6], term[7], term[8]);
    float pm = fmaxf(vmax3(x0, x1, x2), term[9]);
    int st = 9;
    #pragma unroll
    for (int n = 8; n >= 0; --n) st = (term[n] == pm) ? n : st;
    score[b] = pm;

    uint2 wA[16], wB[16];
    auto pre = [&](uint2 (&W)[16], int cb) {
        #pragma unroll
        for (int u = 0; u < 16; ++u) W[u] = gmap[(size_t)(cb * 16 + u) * B_N + b];
    };
    auto proc = [&](uint2 (&W)[16], int cb) {
        #pragma unroll
        for (int u = 15; u >= 0; --u) {
            int cc = cb * 16 + u;
            entry[(size_t)cc * B_N + b] = (unsigned char)st;
            st = bpapply(W[u], st);
        }
    };
    pre(wA, 7);
    pre(wB, 6); proc(wA, 7);
    pre(wA, 5); proc(wB, 6);
    pre(wB, 4); proc(wA, 5);
    pre(wA, 3); proc(wB, 4);
    pre(wB, 2); proc(wA, 3);
    pre(wA, 1); proc(wB, 2);
    pre(wB, 0); proc(wA, 1);
    proc(wB, 0);
}

// ---------------- C: follow maps per (batch, chunk) from entry tag, emit path ----------------
__global__ void __launch_bounds__(256) bt_emit(const unsigned* __restrict__ bpd,
                                               const unsigned char* __restrict__ bpb,
                                               const int* __restrict__ lengths,
                                               const unsigned char* __restrict__ entry,
                                               float* __restrict__ opaths) {
    const int c = blockIdx.x >> 4;
    const int b = ((blockIdx.x & 15) << 8) + threadIdx.x;
    const int len = lengths[b];
    float* op = opaths + (size_t)b * S_LEN + c * 16;

    if (c * 16 >= len) {   // fully past len: all zeros, skip map loads
        float4 z = make_float4(0.f, 0.f, 0.f, 0.f);
        #pragma unroll
        for (int qq = 0; qq < 4; ++qq) *(float4*)(op + qq * 4) = z;
        return;
    }

    const int r0 = c * 16 + 1;
    unsigned Wd[16], Wb[16];
    #pragma unroll
    for (int u = 0; u < 16; ++u) {
        int r = r0 + u;
        unsigned d = 0x76543210u, h = 0x98u;   // identity
        if (r < len) { d = bpd[(size_t)r * B_N + b]; h = bpb[(size_t)r * B_N + b]; }
        Wd[u] = d; Wb[u] = h;
    }

    int cur = entry[(size_t)c * B_N + b];
    float buf[16];
    #pragma unroll
    for (int u = 15; u >= 0; --u) {
        unsigned long long w = ((unsigned long long)Wb[u] << 32) | Wd[u];
        cur = (int)((w >> ((cur * 4) & 63)) & 15ULL);
        buf[u] = (c * 16 + u < len) ? (float)cur : 0.0f;
    }
    #pragma unroll
    for (int qq = 0; qq < 4; ++qq)
        *(float4*)(op + qq * 4) = make_float4(buf[qq*4+0], buf[qq*4+1], buf[qq*4+2], buf[qq*4+3]);
}

extern "C" void kernel_launch(void* const* d_in, const int* in_sizes, int n_in,
                              void* d_out, int out_size, void* d_ws, size_t ws_size,
                              hipStream_t stream) {
    const float* feats   = (const float*)d_in[0];
    const float* trans   = (const float*)d_in[1];
    const int*   lengths = (const int*)d_in[2];
    float* out = (float*)d_out;

    // workspace layout (~67.8 MB)
    char* w = (char*)d_ws;
    float*         ckpt  = (float*)w;          w += (size_t)NCH * B_N * T_N * 4;       // 20,971,520
    unsigned*      bpd   = (unsigned*)w;       w += (size_t)(S_LEN + 1) * B_N * 4;     // 33,570,816
    unsigned char* bpb   = (unsigned char*)w;  w += (size_t)(S_LEN + 1) * B_N;         //  8,392,704
    uint2*         gmap  = (uint2*)w;          w += (size_t)NCH * B_N * 8;             //  4,194,304
    unsigned char* entry = (unsigned char*)w;  w += (size_t)NCH * B_N;                 //    524,288
    float*         lastfv = (float*)w;                                                 //    163,840

    viterbi_fwd<<<B_N / 16, 256, 0, stream>>>(feats, trans, lengths, ckpt);
    bt_maps   <<<NCH * (B_N / 256), 256, 0, stream>>>(feats, trans, lengths, ckpt, bpd, bpb, gmap, lastfv);
    bt_compose<<<B_N / 256, 256, 0, stream>>>(gmap, lastfv, trans, entry, out);
    bt_emit   <<<NCH * (B_N / 256), 256, 0, stream>>>(bpd, bpb, lengths, entry, out + B_N);
}